// Round 1
// baseline (300.530 us; speedup 1.0000x reference)
//
#include <hip/hip_runtime.h>

// Problem shapes (fixed by setup_inputs):
//   tarsent_state [8,512,512] f32, tar_func [8,512] i32
//   refsent_state [8,32,256,512] f32, ref_func [8,32,256] i32
// Outputs flat-concat (all f32; bool masks become 0.0/1.0):
//   tar_aug      [8,5,512]     @ 0
//   tar_aug_mask [8,5]         @ 20480
//   ref_aug      [8,32,5,512]  @ 20520
//   ref_aug_mask [8,32,5]      @ 675880
//   tarpaper     [8,512]       @ 677160
//   tar_mask2    [8]           @ 681256
//   refpaper     [8,32,512]    @ 681264
//   ref_mask2    [8,32]        @ 812336
// total 812592

#define H      512
#define HV     128          // H / 4 (float4 columns)
#define NL     5
#define BIGF   1e11f

#define OFF_TAR_AUG       0
#define OFF_TAR_AUG_MASK  20480
#define OFF_REF_AUG       20520
#define OFF_REF_AUG_MASK  675880
#define OFF_TARPAPER      677160
#define OFF_TAR_MASK2     681256
#define OFF_REFPAPER      681264
#define OFF_REF_MASK2     812336

__device__ inline float4 f4add(float4 a, float4 b) {
    a.x += b.x; a.y += b.y; a.z += b.z; a.w += b.w; return a;
}
__device__ inline float4 f4scale(float4 a, float s) {
    a.x *= s; a.y *= s; a.z *= s; a.w *= s; return a;
}

// One block per segment. Blocks [0,256): ref segments (S=256).
// Blocks [256,264): tar segments (S=512).
// 256 threads: col = tid&127 (float4 column), phase = tid>>7 (sentence parity).
__global__ __launch_bounds__(256) void emenc_kernel(
    const float* __restrict__ tar_state, const int* __restrict__ tar_func,
    const float* __restrict__ ref_state, const int* __restrict__ ref_func,
    float* __restrict__ out)
{
    __shared__ int    sfunc[512];
    __shared__ float4 spart[HV * NL];   // phase-1 partials, 10 KB
    __shared__ int    scnt[NL];

    const int b = blockIdx.x;
    const float* state;
    const int*   func;
    int S;
    float *aug, *augmask, *paper, *mask2;

    if (b < 256) {
        state   = ref_state + (size_t)b * 256 * H;
        func    = ref_func  + b * 256;
        S       = 256;
        aug     = out + OFF_REF_AUG      + (size_t)b * NL * H;
        augmask = out + OFF_REF_AUG_MASK + b * NL;
        paper   = out + OFF_REFPAPER     + (size_t)b * H;
        mask2   = out + OFF_REF_MASK2    + b;
    } else {
        const int q = b - 256;
        state   = tar_state + (size_t)q * 512 * H;
        func    = tar_func  + q * 512;
        S       = 512;
        aug     = out + OFF_TAR_AUG      + (size_t)q * NL * H;
        augmask = out + OFF_TAR_AUG_MASK + q * NL;
        paper   = out + OFF_TARPAPER     + (size_t)q * H;
        mask2   = out + OFF_TAR_MASK2    + q;
    }

    const int tid = threadIdx.x;
    for (int i = tid; i < S; i += 256) sfunc[i] = func[i];
    __syncthreads();

    const int col   = tid & (HV - 1);
    const int phase = tid >> 7;

    float4 a1 = {0,0,0,0}, a2 = {0,0,0,0}, a3 = {0,0,0,0},
           a4 = {0,0,0,0}, a5 = {0,0,0,0};
    int c1 = 0, c2 = 0, c3 = 0, c4 = 0, c5 = 0;

    #pragma unroll 4
    for (int s = phase; s < S; s += 2) {
        float4 v = ((const float4*)(state + (size_t)s * H))[col];
        int l = sfunc[s];
        if      (l == 1) { a1 = f4add(a1, v); c1++; }
        else if (l == 2) { a2 = f4add(a2, v); c2++; }
        else if (l == 3) { a3 = f4add(a3, v); c3++; }
        else if (l == 4) { a4 = f4add(a4, v); c4++; }
        else if (l == 5) { a5 = f4add(a5, v); c5++; }
    }

    if (phase == 1) {
        spart[col * NL + 0] = a1;
        spart[col * NL + 1] = a2;
        spart[col * NL + 2] = a3;
        spart[col * NL + 3] = a4;
        spart[col * NL + 4] = a5;
        if (col == 0) {
            scnt[0] = c1; scnt[1] = c2; scnt[2] = c3; scnt[3] = c4; scnt[4] = c5;
        }
    }
    __syncthreads();

    if (phase == 0) {
        a1 = f4add(a1, spart[col * NL + 0]);
        a2 = f4add(a2, spart[col * NL + 1]);
        a3 = f4add(a3, spart[col * NL + 2]);
        a4 = f4add(a4, spart[col * NL + 3]);
        a5 = f4add(a5, spart[col * NL + 4]);
        c1 += scnt[0]; c2 += scnt[1]; c3 += scnt[2]; c4 += scnt[3]; c5 += scnt[4];

        float4 t  = f4add(f4add(f4add(a1, a2), f4add(a3, a4)), a5);
        const int ct = c1 + c2 + c3 + c4 + c5;

        const float i1 = 1.0f / (c1 > 0 ? (float)c1 : BIGF);
        const float i2 = 1.0f / (c2 > 0 ? (float)c2 : BIGF);
        const float i3 = 1.0f / (c3 > 0 ? (float)c3 : BIGF);
        const float i4 = 1.0f / (c4 > 0 ? (float)c4 : BIGF);
        const float i5 = 1.0f / (c5 > 0 ? (float)c5 : BIGF);
        const float it = 1.0f / (ct > 0 ? (float)ct : BIGF);

        ((float4*)(aug + 0 * H))[col] = f4scale(a1, i1);
        ((float4*)(aug + 1 * H))[col] = f4scale(a2, i2);
        ((float4*)(aug + 2 * H))[col] = f4scale(a3, i3);
        ((float4*)(aug + 3 * H))[col] = f4scale(a4, i4);
        ((float4*)(aug + 4 * H))[col] = f4scale(a5, i5);
        ((float4*)paper)[col]         = f4scale(t,  it);

        if (col == 0) {
            augmask[0] = c1 > 0 ? 1.0f : 0.0f;
            augmask[1] = c2 > 0 ? 1.0f : 0.0f;
            augmask[2] = c3 > 0 ? 1.0f : 0.0f;
            augmask[3] = c4 > 0 ? 1.0f : 0.0f;
            augmask[4] = c5 > 0 ? 1.0f : 0.0f;
            mask2[0]   = ct > 0 ? 1.0f : 0.0f;
        }
    }
}

extern "C" void kernel_launch(void* const* d_in, const int* in_sizes, int n_in,
                              void* d_out, int out_size, void* d_ws, size_t ws_size,
                              hipStream_t stream) {
    const float* tar_state = (const float*)d_in[0];
    const int*   tar_func  = (const int*)d_in[1];
    const float* ref_state = (const float*)d_in[2];
    const int*   ref_func  = (const int*)d_in[3];
    float* out = (float*)d_out;

    emenc_kernel<<<264, 256, 0, stream>>>(tar_state, tar_func, ref_state, ref_func, out);
}

// Round 2
// 214.073 us; speedup vs baseline: 1.4039x; 1.4039x over previous
//
#include <hip/hip_runtime.h>

// Shapes: tarsent [8,512,512] f32, tar_func [8,512] i32,
//         refsent [8,32,256,512] f32, ref_func [8,32,256] i32.
// Output flat-concat f32 (masks as 0.0/1.0):
//   tar_aug[8,5,512]@0  tar_aug_mask[8,5]@20480  ref_aug[8,32,5,512]@20520
//   ref_aug_mask[8,32,5]@675880  tarpaper[8,512]@677160  tar_mask2[8]@681256
//   refpaper[8,32,512]@681264  ref_mask2[8,32]@812336   total 812592

#define H      512
#define HV     128
#define NL     5
#define BIGF   1e11f
#define CHUNK  64

#define OFF_TAR_AUG       0
#define OFF_TAR_AUG_MASK  20480
#define OFF_REF_AUG       20520
#define OFF_REF_AUG_MASK  675880
#define OFF_TARPAPER      677160
#define OFF_TAR_MASK2     681256
#define OFF_REFPAPER      681264
#define OFF_REF_MASK2     812336

#define NCHUNK_REF 4      // 256 sentences / 64
#define NCHUNK_TAR 8      // 512 sentences / 64
#define NBLK1      1088   // 256*4 + 8*8
#define WSUM_ELEMS ((size_t)NBLK1 * NL * H)           // 2,785,280 f32
#define WCNT_OFF_B (WSUM_ELEMS * 4)                   // byte offset of counts
#define WS_NEED    (WCNT_OFF_B + (size_t)NBLK1 * NL * 4)

__device__ inline float4 f4add(float4 a, float4 b) {
    a.x += b.x; a.y += b.y; a.z += b.z; a.w += b.w; return a;
}
__device__ inline float4 f4scale(float4 a, float s) {
    a.x *= s; a.y *= s; a.z *= s; a.w *= s; return a;
}

// ---------------- Stage 1: per-(segment,chunk) partial label sums ----------
// Blocks [0,1024): ref  seg=b>>2, chunk=b&3.
// Blocks [1024,1088): tar  seg=(b-1024)>>3, chunk=(b-1024)&7.
__global__ __launch_bounds__(256) void emenc_stage1(
    const float* __restrict__ tar_state, const int* __restrict__ tar_func,
    const float* __restrict__ ref_state, const int* __restrict__ ref_func,
    float* __restrict__ wsum, int* __restrict__ wcnt)
{
    __shared__ int    sfunc[CHUNK];
    __shared__ float4 spart[HV * NL];
    __shared__ int    scnt[NL];

    const int b = blockIdx.x;
    const float* state;
    const int*   func;
    int s0;
    if (b < 1024) {
        const int seg = b >> 2, ch = b & 3;
        state = ref_state + (size_t)seg * 256 * H;
        func  = ref_func  + seg * 256;
        s0    = ch * CHUNK;
    } else {
        const int q = b - 1024;
        const int seg = q >> 3, ch = q & 7;
        state = tar_state + (size_t)seg * 512 * H;
        func  = tar_func  + seg * 512;
        s0    = ch * CHUNK;
    }

    const int tid = threadIdx.x;
    if (tid < CHUNK) sfunc[tid] = func[s0 + tid];
    __syncthreads();

    const int col   = tid & (HV - 1);
    const int phase = tid >> 7;

    float4 a1 = {0,0,0,0}, a2 = {0,0,0,0}, a3 = {0,0,0,0},
           a4 = {0,0,0,0}, a5 = {0,0,0,0};
    int c1 = 0, c2 = 0, c3 = 0, c4 = 0, c5 = 0;

    const float* base = state + (size_t)s0 * H;
    #pragma unroll 8
    for (int i = phase; i < CHUNK; i += 2) {
        float4 v = ((const float4*)(base + (size_t)i * H))[col];
        int l = sfunc[i];
        if      (l == 1) { a1 = f4add(a1, v); c1++; }
        else if (l == 2) { a2 = f4add(a2, v); c2++; }
        else if (l == 3) { a3 = f4add(a3, v); c3++; }
        else if (l == 4) { a4 = f4add(a4, v); c4++; }
        else if (l == 5) { a5 = f4add(a5, v); c5++; }
    }

    if (phase == 1) {
        spart[col * NL + 0] = a1;
        spart[col * NL + 1] = a2;
        spart[col * NL + 2] = a3;
        spart[col * NL + 3] = a4;
        spart[col * NL + 4] = a5;
        if (col == 0) {
            scnt[0] = c1; scnt[1] = c2; scnt[2] = c3; scnt[3] = c4; scnt[4] = c5;
        }
    }
    __syncthreads();

    if (phase == 0) {
        a1 = f4add(a1, spart[col * NL + 0]);
        a2 = f4add(a2, spart[col * NL + 1]);
        a3 = f4add(a3, spart[col * NL + 2]);
        a4 = f4add(a4, spart[col * NL + 3]);
        a5 = f4add(a5, spart[col * NL + 4]);

        float* wb = wsum + (size_t)b * NL * H;
        ((float4*)(wb + 0 * H))[col] = a1;
        ((float4*)(wb + 1 * H))[col] = a2;
        ((float4*)(wb + 2 * H))[col] = a3;
        ((float4*)(wb + 3 * H))[col] = a4;
        ((float4*)(wb + 4 * H))[col] = a5;

        if (col == 0) {
            wcnt[b * NL + 0] = c1 + scnt[0];
            wcnt[b * NL + 1] = c2 + scnt[1];
            wcnt[b * NL + 2] = c3 + scnt[2];
            wcnt[b * NL + 3] = c4 + scnt[3];
            wcnt[b * NL + 4] = c5 + scnt[4];
        }
    }
}

// ---------------- Stage 2: combine chunks, divide, write outputs ----------
// Blocks [0,256): ref segments; [256,264): tar segments. 128 threads = cols.
__global__ __launch_bounds__(128) void emenc_stage2(
    const float* __restrict__ wsum, const int* __restrict__ wcnt,
    float* __restrict__ out)
{
    __shared__ int scnt[NCHUNK_TAR * NL];

    const int b = blockIdx.x;
    int nch, wb0;
    float *aug, *augmask, *paper, *mask2;
    if (b < 256) {
        nch = NCHUNK_REF; wb0 = b * NCHUNK_REF;
        aug     = out + OFF_REF_AUG      + (size_t)b * NL * H;
        augmask = out + OFF_REF_AUG_MASK + b * NL;
        paper   = out + OFF_REFPAPER     + (size_t)b * H;
        mask2   = out + OFF_REF_MASK2    + b;
    } else {
        const int q = b - 256;
        nch = NCHUNK_TAR; wb0 = 1024 + q * NCHUNK_TAR;
        aug     = out + OFF_TAR_AUG      + (size_t)q * NL * H;
        augmask = out + OFF_TAR_AUG_MASK + q * NL;
        paper   = out + OFF_TARPAPER     + (size_t)q * H;
        mask2   = out + OFF_TAR_MASK2    + q;
    }

    const int tid = threadIdx.x;
    if (tid < nch * NL) scnt[tid] = wcnt[wb0 * NL + tid];
    __syncthreads();

    int c[NL], ct = 0;
    #pragma unroll
    for (int l = 0; l < NL; l++) {
        int s = 0;
        for (int ch = 0; ch < nch; ch++) s += scnt[ch * NL + l];
        c[l] = s; ct += s;
    }

    const int col = tid;       // 128 float4 columns
    float4 tot = {0,0,0,0};
    #pragma unroll
    for (int l = 0; l < NL; l++) {
        float4 s = {0,0,0,0};
        for (int ch = 0; ch < nch; ch++) {
            s = f4add(s, ((const float4*)(wsum + (size_t)(wb0 + ch) * NL * H
                                          + (size_t)l * H))[col]);
        }
        tot = f4add(tot, s);
        const float inv = 1.0f / (c[l] > 0 ? (float)c[l] : BIGF);
        ((float4*)(aug + (size_t)l * H))[col] = f4scale(s, inv);
    }
    ((float4*)paper)[col] = f4scale(tot, 1.0f / (ct > 0 ? (float)ct : BIGF));

    if (col == 0) {
        #pragma unroll
        for (int l = 0; l < NL; l++) augmask[l] = c[l] > 0 ? 1.0f : 0.0f;
        mask2[0] = ct > 0 ? 1.0f : 0.0f;
    }
}

// ---------------- Fallback (round-1 single-stage) if ws too small ----------
__global__ __launch_bounds__(256) void emenc_single(
    const float* __restrict__ tar_state, const int* __restrict__ tar_func,
    const float* __restrict__ ref_state, const int* __restrict__ ref_func,
    float* __restrict__ out)
{
    __shared__ int    sfunc[512];
    __shared__ float4 spart[HV * NL];
    __shared__ int    scnt[NL];

    const int b = blockIdx.x;
    const float* state;
    const int*   func;
    int S;
    float *aug, *augmask, *paper, *mask2;

    if (b < 256) {
        state   = ref_state + (size_t)b * 256 * H;
        func    = ref_func  + b * 256;
        S       = 256;
        aug     = out + OFF_REF_AUG      + (size_t)b * NL * H;
        augmask = out + OFF_REF_AUG_MASK + b * NL;
        paper   = out + OFF_REFPAPER     + (size_t)b * H;
        mask2   = out + OFF_REF_MASK2    + b;
    } else {
        const int q = b - 256;
        state   = tar_state + (size_t)q * 512 * H;
        func    = tar_func  + q * 512;
        S       = 512;
        aug     = out + OFF_TAR_AUG      + (size_t)q * NL * H;
        augmask = out + OFF_TAR_AUG_MASK + q * NL;
        paper   = out + OFF_TARPAPER     + (size_t)q * H;
        mask2   = out + OFF_TAR_MASK2    + q;
    }

    const int tid = threadIdx.x;
    for (int i = tid; i < S; i += 256) sfunc[i] = func[i];
    __syncthreads();

    const int col   = tid & (HV - 1);
    const int phase = tid >> 7;

    float4 a1 = {0,0,0,0}, a2 = {0,0,0,0}, a3 = {0,0,0,0},
           a4 = {0,0,0,0}, a5 = {0,0,0,0};
    int c1 = 0, c2 = 0, c3 = 0, c4 = 0, c5 = 0;

    #pragma unroll 4
    for (int s = phase; s < S; s += 2) {
        float4 v = ((const float4*)(state + (size_t)s * H))[col];
        int l = sfunc[s];
        if      (l == 1) { a1 = f4add(a1, v); c1++; }
        else if (l == 2) { a2 = f4add(a2, v); c2++; }
        else if (l == 3) { a3 = f4add(a3, v); c3++; }
        else if (l == 4) { a4 = f4add(a4, v); c4++; }
        else if (l == 5) { a5 = f4add(a5, v); c5++; }
    }

    if (phase == 1) {
        spart[col * NL + 0] = a1;
        spart[col * NL + 1] = a2;
        spart[col * NL + 2] = a3;
        spart[col * NL + 3] = a4;
        spart[col * NL + 4] = a5;
        if (col == 0) {
            scnt[0] = c1; scnt[1] = c2; scnt[2] = c3; scnt[3] = c4; scnt[4] = c5;
        }
    }
    __syncthreads();

    if (phase == 0) {
        a1 = f4add(a1, spart[col * NL + 0]);
        a2 = f4add(a2, spart[col * NL + 1]);
        a3 = f4add(a3, spart[col * NL + 2]);
        a4 = f4add(a4, spart[col * NL + 3]);
        a5 = f4add(a5, spart[col * NL + 4]);
        c1 += scnt[0]; c2 += scnt[1]; c3 += scnt[2]; c4 += scnt[3]; c5 += scnt[4];

        float4 t  = f4add(f4add(f4add(a1, a2), f4add(a3, a4)), a5);
        const int ct = c1 + c2 + c3 + c4 + c5;

        ((float4*)(aug + 0 * H))[col] = f4scale(a1, 1.0f / (c1 > 0 ? (float)c1 : BIGF));
        ((float4*)(aug + 1 * H))[col] = f4scale(a2, 1.0f / (c2 > 0 ? (float)c2 : BIGF));
        ((float4*)(aug + 2 * H))[col] = f4scale(a3, 1.0f / (c3 > 0 ? (float)c3 : BIGF));
        ((float4*)(aug + 3 * H))[col] = f4scale(a4, 1.0f / (c4 > 0 ? (float)c4 : BIGF));
        ((float4*)(aug + 4 * H))[col] = f4scale(a5, 1.0f / (c5 > 0 ? (float)c5 : BIGF));
        ((float4*)paper)[col]         = f4scale(t,  1.0f / (ct > 0 ? (float)ct : BIGF));

        if (col == 0) {
            augmask[0] = c1 > 0 ? 1.0f : 0.0f;
            augmask[1] = c2 > 0 ? 1.0f : 0.0f;
            augmask[2] = c3 > 0 ? 1.0f : 0.0f;
            augmask[3] = c4 > 0 ? 1.0f : 0.0f;
            augmask[4] = c5 > 0 ? 1.0f : 0.0f;
            mask2[0]   = ct > 0 ? 1.0f : 0.0f;
        }
    }
}

extern "C" void kernel_launch(void* const* d_in, const int* in_sizes, int n_in,
                              void* d_out, int out_size, void* d_ws, size_t ws_size,
                              hipStream_t stream) {
    const float* tar_state = (const float*)d_in[0];
    const int*   tar_func  = (const int*)d_in[1];
    const float* ref_state = (const float*)d_in[2];
    const int*   ref_func  = (const int*)d_in[3];
    float* out = (float*)d_out;

    if (ws_size >= WS_NEED) {
        float* wsum = (float*)d_ws;
        int*   wcnt = (int*)((char*)d_ws + WCNT_OFF_B);
        emenc_stage1<<<NBLK1, 256, 0, stream>>>(tar_state, tar_func,
                                                ref_state, ref_func, wsum, wcnt);
        emenc_stage2<<<264, 128, 0, stream>>>(wsum, wcnt, out);
    } else {
        emenc_single<<<264, 256, 0, stream>>>(tar_state, tar_func,
                                              ref_state, ref_func, out);
    }
}